// Round 1
// baseline (72.961 us; speedup 1.0000x reference)
//
#include <hip/hip_runtime.h>

typedef __attribute__((ext_vector_type(4))) float f32x4;
typedef __attribute__((ext_vector_type(8))) short short8;
typedef unsigned int u32;
typedef unsigned long long u64;
typedef unsigned short u16;

#define NB 512
#define TT 256
#define CC 384
#define HH 64

__device__ __forceinline__ u16 fbf(float f) {
    u32 u = __builtin_bit_cast(u32, f);
    u32 r = u + 0x7fffu + ((u >> 16) & 1u);
    return (u16)(r >> 16);
}

__device__ __forceinline__ f32x4 mfma16x16x32(short8 a, short8 b, f32x4 c) {
    return __builtin_amdgcn_mfma_f32_16x16x32_bf16(a, b, c, 0, 0, 0);
}

// WbT layout: fragment fi = ((mat*12 + kt)*4 + nt); element (fi*64 + lane)*8 + j
//   = W[mat][c = 32*kt + 8*(lane>>4) + j][h = 16*nt + (lane&15)]
// mat 0 = Wq * 384^-0.5 (scale folded), 1 = Wk, 2 = Wv.
__global__ __launch_bounds__(256) void prep_w(const float* __restrict__ Wk,
                                              const float* __restrict__ Wq,
                                              const float* __restrict__ Wv,
                                              u16* __restrict__ WbT) {
    int t = blockIdx.x * 256 + threadIdx.x;
    if (t >= 144 * 64) return;
    int lane = t & 63;
    int fi = t >> 6;
    int mat = fi / 48;
    int kt = (fi >> 2) % 12;
    int nt = fi & 3;
    const float* W = (mat == 0) ? Wq : (mat == 1 ? Wk : Wv);
    float scale = (mat == 0) ? 0.05103103630798288f : 1.0f;
    int c0 = 32 * kt + 8 * (lane >> 4);
    int h = 16 * nt + (lane & 15);
#pragma unroll
    for (int j = 0; j < 8; ++j)
        WbT[(size_t)t * 8 + j] = fbf(W[(c0 + j) * HH + h] * scale);
}

// One block per batch. 8 waves; wave w owns q-rows [32w, 32w+32).
// LDS: K row-major [256][64] bf16 (swizzled), Vt [64][256] bf16 (swizzled),
//      per-wave 32x64 scratch (Q transpose, then P transpose per chunk).
__global__ __launch_bounds__(512) void attn_head(const float* __restrict__ x,
                                                 const u16* __restrict__ WbT,
                                                 float* __restrict__ out) {
    __shared__ __align__(16) u16 Klds[TT * HH];
    __shared__ __align__(16) u16 Vtlds[HH * TT];
    __shared__ __align__(16) u16 Pscr[8 * 32 * 64];

    const int tid = (int)threadIdx.x;
    const int lane = tid & 63;
    const int w = tid >> 6;
    const int c = lane & 15;
    const int g = lane >> 4;
    const int b = (int)blockIdx.x;
    const int m0 = 32 * w;

    char* kbase = (char*)Klds;
    char* vbase = (char*)Vtlds;
    char* sbase = (char*)(Pscr + w * 2048);

    // ---------------- projection: Q,K,V = x[b] @ W ----------------
    f32x4 acc[3][2][4];
#pragma unroll
    for (int m = 0; m < 3; ++m)
#pragma unroll
        for (int tm = 0; tm < 2; ++tm)
#pragma unroll
            for (int nt = 0; nt < 4; ++nt)
                acc[m][tm][nt] = (f32x4){0.f, 0.f, 0.f, 0.f};

    const float* xb = x + (size_t)b * TT * CC;

    for (int kt = 0; kt < 12; ++kt) {
        short8 afr[2];
#pragma unroll
        for (int tm = 0; tm < 2; ++tm) {
            const float* p = xb + (size_t)(m0 + 16 * tm + c) * CC + 32 * kt + 8 * g;
            f32x4 f0 = *(const f32x4*)p;
            f32x4 f1 = *(const f32x4*)(p + 4);
            short8 a;
            a[0] = (short)fbf(f0[0]); a[1] = (short)fbf(f0[1]);
            a[2] = (short)fbf(f0[2]); a[3] = (short)fbf(f0[3]);
            a[4] = (short)fbf(f1[0]); a[5] = (short)fbf(f1[1]);
            a[6] = (short)fbf(f1[2]); a[7] = (short)fbf(f1[3]);
            afr[tm] = a;
        }
#pragma unroll
        for (int mat = 0; mat < 3; ++mat) {
#pragma unroll
            for (int nt = 0; nt < 4; ++nt) {
                short8 bfr = *(const short8*)(WbT + (size_t)(((mat * 12 + kt) * 4 + nt) * 64 + lane) * 8);
                acc[mat][0][nt] = mfma16x16x32(afr[0], bfr, acc[mat][0][nt]);
                acc[mat][1][nt] = mfma16x16x32(afr[1], bfr, acc[mat][1][nt]);
            }
        }
    }

    // ---- Q: D-layout -> per-wave scratch -> B-fragment registers ----
#pragma unroll
    for (int tm = 0; tm < 2; ++tm)
#pragma unroll
        for (int nt = 0; nt < 4; ++nt)
#pragma unroll
            for (int r = 0; r < 4; ++r) {
                int q = 16 * tm + 4 * g + r;
                int hh = 16 * nt + c;
                *(u16*)(sbase + q * 128 + ((hh * 2) ^ ((q & 7) << 4))) = fbf(acc[0][tm][nt][r]);
            }
    short8 Qf[2][2];
#pragma unroll
    for (int tm = 0; tm < 2; ++tm)
#pragma unroll
        for (int kt = 0; kt < 2; ++kt) {
            int q = 16 * tm + c;
            Qf[tm][kt] = *(const short8*)(sbase + q * 128 + ((64 * kt + 16 * g) ^ ((q & 7) << 4)));
        }

    // ---- K row-major (swizzled), V transposed (swizzled) into LDS ----
#pragma unroll
    for (int tm = 0; tm < 2; ++tm)
#pragma unroll
        for (int nt = 0; nt < 4; ++nt) {
            int hh = 16 * nt + c;
#pragma unroll
            for (int r = 0; r < 4; ++r) {
                int s = m0 + 16 * tm + 4 * g + r;
                *(u16*)(kbase + s * 128 + ((hh * 2) ^ ((s & 7) << 4))) = fbf(acc[1][tm][nt][r]);
            }
            int sb4 = m0 + 16 * tm + 4 * g;
            u64 pk = (u64)fbf(acc[2][tm][nt][0]) | ((u64)fbf(acc[2][tm][nt][1]) << 16) |
                     ((u64)fbf(acc[2][tm][nt][2]) << 32) | ((u64)fbf(acc[2][tm][nt][3]) << 48);
            *(u64*)(vbase + hh * 512 + ((sb4 * 2) ^ ((hh & 7) << 4))) = pk;
        }

    __syncthreads();

    // ---------------- attention, online softmax over 64-wide s-chunks ----------------
    float m_run0 = -1e30f, m_run1 = -1e30f, l_run0 = 0.f, l_run1 = 0.f;
    f32x4 o[2][4];
#pragma unroll
    for (int tm = 0; tm < 2; ++tm)
#pragma unroll
        for (int ht = 0; ht < 4; ++ht)
            o[tm][ht] = (f32x4){0.f, 0.f, 0.f, 0.f};

    const int nch = (w >> 1) + 1;
    for (int ci = 0; ci < nch; ++ci) {
        const int s0 = 64 * ci;
        int stmax = (m0 + 31 - s0) >> 4;
        stmax = stmax > 3 ? 3 : stmax;

        // S^T = K(16s x 32h) x Q^T(32h x 16q); lane: s = 4g+r (rows), q = c (cols)
        f32x4 SS[4][2];
#pragma unroll
        for (int st = 0; st < 4; ++st) {
            SS[st][0] = (f32x4){0.f, 0.f, 0.f, 0.f};
            SS[st][1] = (f32x4){0.f, 0.f, 0.f, 0.f};
        }
#pragma unroll
        for (int kt = 0; kt < 2; ++kt) {
#pragma unroll
            for (int st = 0; st < 4; ++st) {
                if (st <= stmax) {
                    int s = s0 + 16 * st + c;
                    short8 kf = *(const short8*)(kbase + s * 128 + ((64 * kt + 16 * g) ^ ((s & 7) << 4)));
                    SS[st][0] = mfma16x16x32(kf, Qf[0][kt], SS[st][0]);
                    SS[st][1] = mfma16x16x32(kf, Qf[1][kt], SS[st][1]);
                }
            }
        }

        // causal mask + chunk max
        float mx0 = -1e30f, mx1 = -1e30f;
        const int qg0 = m0 + c, qg1 = m0 + 16 + c;
#pragma unroll
        for (int st = 0; st < 4; ++st) {
            if (st > stmax) continue;
#pragma unroll
            for (int r = 0; r < 4; ++r) {
                int sg = s0 + 16 * st + 4 * g + r;
                float v0 = SS[st][0][r], v1 = SS[st][1][r];
                v0 = (sg > qg0) ? -1e30f : v0;
                v1 = (sg > qg1) ? -1e30f : v1;
                SS[st][0][r] = v0; SS[st][1][r] = v1;
                mx0 = fmaxf(mx0, v0); mx1 = fmaxf(mx1, v1);
            }
        }
        mx0 = fmaxf(mx0, __shfl_xor(mx0, 16));
        mx0 = fmaxf(mx0, __shfl_xor(mx0, 32));
        mx1 = fmaxf(mx1, __shfl_xor(mx1, 16));
        mx1 = fmaxf(mx1, __shfl_xor(mx1, 32));

        float mn0 = fmaxf(m_run0, mx0), mn1 = fmaxf(m_run1, mx1);
        float fs0 = __expf(m_run0 - mn0), fs1 = __expf(m_run1 - mn1);
        m_run0 = mn0; m_run1 = mn1;

        float ls0 = 0.f, ls1 = 0.f;
#pragma unroll
        for (int st = 0; st < 4; ++st) {
            if (st > stmax) continue;
#pragma unroll
            for (int r = 0; r < 4; ++r) {
                float p0 = __expf(SS[st][0][r] - mn0);
                float p1 = __expf(SS[st][1][r] - mn1);
                SS[st][0][r] = p0; SS[st][1][r] = p1;
                ls0 += p0; ls1 += p1;
            }
        }
        ls0 += __shfl_xor(ls0, 16); ls0 += __shfl_xor(ls0, 32);
        ls1 += __shfl_xor(ls1, 16); ls1 += __shfl_xor(ls1, 32);
        l_run0 = l_run0 * fs0 + ls0;
        l_run1 = l_run1 * fs1 + ls1;

        // rescale O accumulators: O rows are q = 4g+r -> fetch f for that row
#pragma unroll
        for (int r = 0; r < 4; ++r) {
            float fr0 = __shfl(fs0, (g << 2) + r);
            float fr1 = __shfl(fs1, (g << 2) + r);
#pragma unroll
            for (int ht = 0; ht < 4; ++ht) {
                o[0][ht][r] *= fr0;
                o[1][ht][r] *= fr1;
            }
        }

        // P (bf16) -> per-wave scratch [32 q][64 s] (swizzled)
#pragma unroll
        for (int st = 0; st < 4; ++st) {
            if (st > stmax) continue;
#pragma unroll
            for (int tm = 0; tm < 2; ++tm) {
                int ql = 16 * tm + c;
                u32 lo = (u32)fbf(SS[st][tm][0]) | ((u32)fbf(SS[st][tm][1]) << 16);
                u32 hi = (u32)fbf(SS[st][tm][2]) | ((u32)fbf(SS[st][tm][3]) << 16);
                *(u64*)(sbase + ql * 128 + ((32 * st + 8 * g) ^ ((ql & 7) << 4))) = (u64)lo | ((u64)hi << 32);
            }
        }

        // PV: O += P(16q x 32s) x V(32s x 16h)
        const int ksmax = stmax >> 1;
#pragma unroll
        for (int ks = 0; ks < 2; ++ks) {
            if (ks > ksmax) continue;
            short8 Pf0 = *(const short8*)(sbase + c * 128 + ((64 * ks + 16 * g) ^ ((c & 7) << 4)));
            short8 Pf1 = *(const short8*)(sbase + (16 + c) * 128 + ((64 * ks + 16 * g) ^ ((c & 7) << 4)));
#pragma unroll
            for (int ht = 0; ht < 4; ++ht) {
                int hh = 16 * ht + c;
                short8 vf = *(const short8*)(vbase + hh * 512 + ((2 * s0 + 64 * ks + 16 * g) ^ ((hh & 7) << 4)));
                o[0][ht] = mfma16x16x32(Pf0, vf, o[0][ht]);
                o[1][ht] = mfma16x16x32(Pf1, vf, o[1][ht]);
            }
        }
    }

    // ---------------- epilogue: divide by l, store fp32 ----------------
    float* ob = out + ((size_t)b * TT + m0) * HH;
    float ri0 = 1.f / l_run0, ri1 = 1.f / l_run1;
#pragma unroll
    for (int r = 0; r < 4; ++r) {
        float rr0 = __shfl(ri0, (g << 2) + r);
        float rr1 = __shfl(ri1, (g << 2) + r);
#pragma unroll
        for (int ht = 0; ht < 4; ++ht) {
            ob[(4 * g + r) * HH + 16 * ht + c] = o[0][ht][r] * rr0;
            ob[(16 + 4 * g + r) * HH + 16 * ht + c] = o[1][ht][r] * rr1;
        }
    }
}

extern "C" void kernel_launch(void* const* d_in, const int* in_sizes, int n_in,
                              void* d_out, int out_size, void* d_ws, size_t ws_size,
                              hipStream_t stream) {
    (void)in_sizes; (void)n_in; (void)out_size; (void)ws_size;
    const float* x = (const float*)d_in[0];
    const float* Wk = (const float*)d_in[1];
    const float* Wq = (const float*)d_in[2];
    const float* Wv = (const float*)d_in[3];
    u16* WbT = (u16*)d_ws;
    float* out = (float*)d_out;

    prep_w<<<36, 256, 0, stream>>>(Wk, Wq, Wv, WbT);
    attn_head<<<NB, 512, 0, stream>>>(x, WbT, out);
}